// Round 1
// baseline (8554.442 us; speedup 1.0000x reference)
//
#include <hip/hip_runtime.h>

// ---------------- problem dims ----------------
#define N_SEQ   64
#define T_LEN   512
#define IN_SZ   512
#define HID     1024
#define ODIM    256

// ---------------- kernel config ----------------
#define REC_WGS   128          // each owns 8 h-columns
#define PROJ_WGS  16           // each owns 16 output columns
#define TOT_WGS   (REC_WGS + PROJ_WGS)
#define CPW       8            // h-cols per rec WG
#define GCOLS     32           // gate cols per rec WG (4 gates x 8)

#define WH_LD 1032             // padded LDS leading dims (halves)
#define WI_LD 520
#define GLD   33               // gate scratch stride (floats)
#define WP_LD 1032

typedef _Float16 half8 __attribute__((ext_vector_type(8)));
typedef _Float16 half4 __attribute__((ext_vector_type(4)));
typedef float    f32x4 __attribute__((ext_vector_type(4)));

// LDS layout (bytes), rec role
#define WH_OFF   0
#define WI_OFF   (GCOLS*WH_LD*2)                 // 66048
#define GATE_OFF (WI_OFF + GCOLS*WI_LD*2)        // 99328
#define BIAS_OFF (GATE_OFF + 64*GLD*4)           // 107776
#define LDS_BYTES (BIAS_OFF + 128)               // 107904
// proj role overlays the same dynamic LDS
#define PB_OFF   (16*WP_LD*2)                    // 33024

// ws layout (bytes)
#define HBUF_OFF 4096                            // 2 x [64][1024] fp16 = 256 KiB
#define XBUF_OFF 524288                          // obs converted to fp16: 32 MiB

__device__ __forceinline__ float sigmf(float x) { return 1.f / (1.f + expf(-x)); }

// sharded grid barrier: 8 shards x 18 blocks, relaxed agent atomics + fences
__device__ __forceinline__ void gbar(unsigned* bar, int bid, unsigned target) {
  __syncthreads();
  if (threadIdx.x == 0) {
    __threadfence();   // push h stores (and everything else) to coherence point
    unsigned* cnt = bar + 32 + 16 * (bid & 7);
    unsigned v = __hip_atomic_fetch_add(cnt, 1u, __ATOMIC_RELAXED, __HIP_MEMORY_SCOPE_AGENT);
    if (v == (TOT_WGS / 8) - 1) {
      __hip_atomic_store(cnt, 0u, __ATOMIC_RELAXED, __HIP_MEMORY_SCOPE_AGENT);
      unsigned m = __hip_atomic_fetch_add(bar + 16, 1u, __ATOMIC_RELAXED, __HIP_MEMORY_SCOPE_AGENT);
      if (m == 7u) {
        __hip_atomic_store(bar + 16, 0u, __ATOMIC_RELAXED, __HIP_MEMORY_SCOPE_AGENT);
        __hip_atomic_fetch_add(bar, 1u, __ATOMIC_RELAXED, __HIP_MEMORY_SCOPE_AGENT);
      }
    }
    while (__hip_atomic_load(bar, __ATOMIC_RELAXED, __HIP_MEMORY_SCOPE_AGENT) < target) {
      __builtin_amdgcn_s_sleep(1);
    }
    __threadfence();   // make other blocks' h stores visible to my block
  }
  __syncthreads();
}

// init: zero barrier region, h_buf[1] <- fp16(h0)
__global__ void init_kernel(const float* __restrict__ h0, unsigned char* __restrict__ ws) {
  int idx = blockIdx.x * 256 + threadIdx.x;
  if (idx < 1024) ((unsigned*)ws)[idx] = 0u;
  _Float16* h1 = (_Float16*)(ws + HBUF_OFF) + (size_t)N_SEQ * HID;  // buffer parity 1
  for (int i = idx; i < N_SEQ * HID; i += gridDim.x * 256) h1[i] = (_Float16)h0[i];
}

// obs fp32 -> fp16 (same [n*T+t][k] layout)
__global__ void cvt_obs(const float* __restrict__ obs, unsigned char* __restrict__ ws) {
  _Float16* xf = (_Float16*)(ws + XBUF_OFF);
  const size_t n = (size_t)N_SEQ * T_LEN * IN_SZ;
  for (size_t i = ((size_t)blockIdx.x * 256 + threadIdx.x) * 4; i < n;
       i += (size_t)gridDim.x * 256 * 4) {
    f32x4 v = *(const f32x4*)(obs + i);
    half4 h; h[0] = (_Float16)v[0]; h[1] = (_Float16)v[1];
    h[2] = (_Float16)v[2]; h[3] = (_Float16)v[3];
    *(half4*)(xf + i) = h;
  }
}

__launch_bounds__(256, 1)
__global__ void lstm_coop(const float* __restrict__ c0,
                          const float* __restrict__ es,
                          const float* __restrict__ W_ih,
                          const float* __restrict__ W_hh,
                          const float* __restrict__ b_ih,
                          const float* __restrict__ b_hh,
                          const float* __restrict__ W_proj,
                          const float* __restrict__ b_proj,
                          float* __restrict__ out,
                          unsigned char* __restrict__ ws) {
  extern __shared__ char smem[];
  const int tid = threadIdx.x;
  const int bid = blockIdx.x;
  unsigned* bar = (unsigned*)ws;
  _Float16* hb0 = (_Float16*)(ws + HBUF_OFF);
  _Float16* hb1 = hb0 + (size_t)N_SEQ * HID;
  const _Float16* xf = (const _Float16*)(ws + XBUF_OFF);

  const int w = tid >> 6, lane = tid & 63, lr = lane & 15, lg = lane >> 4;

  if (bid < REC_WGS) {
    _Float16* wh = (_Float16*)(smem + WH_OFF);
    _Float16* wi = (_Float16*)(smem + WI_OFF);
    float* gate = (float*)(smem + GATE_OFF);
    float* bias = (float*)(smem + BIAS_OFF);

    // stage weight slices (gate order i,f,g,o; col c = gate*8 + jl)
    for (int idx = tid; idx < GCOLS * IN_SZ; idx += 256) {
      int c = idx >> 9, k = idx & (IN_SZ - 1);
      int grow = (c >> 3) * HID + bid * CPW + (c & 7);
      wi[c * WI_LD + k] = (_Float16)W_ih[(size_t)grow * IN_SZ + k];
    }
    for (int idx = tid; idx < GCOLS * HID; idx += 256) {
      int c = idx >> 10, k = idx & (HID - 1);
      int grow = (c >> 3) * HID + bid * CPW + (c & 7);
      wh[c * WH_LD + k] = (_Float16)W_hh[(size_t)grow * HID + k];
    }
    if (tid < GCOLS) {
      int grow = (tid >> 3) * HID + bid * CPW + (tid & 7);
      bias[tid] = b_ih[grow] + b_hh[grow];
    }
    const int erow = tid >> 2, ej = tid & 3;   // epilogue mapping: 64 rows x 4
    float creg0 = c0[erow * HID + bid * CPW + ej];
    float creg1 = c0[erow * HID + bid * CPW + ej + 4];
    __syncthreads();

    const int arow = 16 * w + lr;              // sequence index for A fragments
    for (int t = 0; t < T_LEN; ++t) {
      const _Float16* hprev = ((t + 1) & 1) ? hb1 : hb0;
      float esv = es[arow * T_LEN + t];
      bool kill = (esv != 0.f);
      f32x4 acc0 = {0.f, 0.f, 0.f, 0.f}, acc1 = {0.f, 0.f, 0.f, 0.f};

      // x part: K = 512
      const _Float16* xrow = xf + ((size_t)arow * T_LEN + t) * IN_SZ;
      #pragma unroll 8
      for (int kb = 0; kb < IN_SZ / 32; ++kb) {
        int k0 = kb * 32 + lg * 8;
        half8 a = *(const half8*)(xrow + k0);
        half8 b0v = *(const half8*)(wi + lr * WI_LD + k0);
        half8 b1v = *(const half8*)(wi + (16 + lr) * WI_LD + k0);
        acc0 = __builtin_amdgcn_mfma_f32_16x16x32_f16(a, b0v, acc0, 0, 0, 0);
        acc1 = __builtin_amdgcn_mfma_f32_16x16x32_f16(a, b1v, acc1, 0, 0, 0);
      }
      // h part: K = 1024, masked by episode_starts
      const _Float16* hrow = hprev + (size_t)arow * HID;
      half8 z8 = {};
      #pragma unroll 8
      for (int kb = 0; kb < HID / 32; ++kb) {
        int k0 = kb * 32 + lg * 8;
        half8 a = *(const half8*)(hrow + k0);
        if (kill) a = z8;
        half8 b0v = *(const half8*)(wh + lr * WH_LD + k0);
        half8 b1v = *(const half8*)(wh + (16 + lr) * WH_LD + k0);
        acc0 = __builtin_amdgcn_mfma_f32_16x16x32_f16(a, b0v, acc0, 0, 0, 0);
        acc1 = __builtin_amdgcn_mfma_f32_16x16x32_f16(a, b1v, acc1, 0, 0, 0);
      }
      // C/D layout: col = lane&15, row = (lane>>4)*4 + r  (verified m89)
      #pragma unroll
      for (int r = 0; r < 4; ++r) {
        int row = 16 * w + lg * 4 + r;
        gate[row * GLD + lr] = acc0[r];
        gate[row * GLD + 16 + lr] = acc1[r];
      }
      __syncthreads();

      // LSTM pointwise epilogue: 256 threads x 2 h-cols
      {
        float m = 1.f - es[erow * T_LEN + t];
        _Float16* hc = (t & 1) ? hb1 : hb0;
        const float* g = gate + erow * GLD;
        float pi = g[ej] + bias[ej];
        float pf = g[8 + ej] + bias[8 + ej];
        float pg = g[16 + ej] + bias[16 + ej];
        float po = g[24 + ej] + bias[24 + ej];
        float cv = sigmf(pf) * (creg0 * m) + sigmf(pi) * tanhf(pg);
        creg0 = cv;
        hc[erow * HID + bid * CPW + ej] = (_Float16)(sigmf(po) * tanhf(cv));

        pi = g[4 + ej] + bias[4 + ej];
        pf = g[12 + ej] + bias[12 + ej];
        pg = g[20 + ej] + bias[20 + ej];
        po = g[28 + ej] + bias[28 + ej];
        cv = sigmf(pf) * (creg1 * m) + sigmf(pi) * tanhf(pg);
        creg1 = cv;
        hc[erow * HID + bid * CPW + 4 + ej] = (_Float16)(sigmf(po) * tanhf(cv));
      }
      gbar(bar, bid, (unsigned)(t + 1));
    }
  } else {
    // ---------------- projection role ----------------
    _Float16* wp = (_Float16*)smem;
    float* pb = (float*)(smem + PB_OFF);
    const int p = bid - REC_WGS;
    for (int idx = tid; idx < 16 * HID; idx += 256) {
      int c = idx >> 10, k = idx & (HID - 1);
      wp[c * WP_LD + k] = (_Float16)W_proj[(size_t)k * ODIM + p * 16 + c];
    }
    if (tid < 16) pb[tid] = b_proj[p * 16 + tid];
    __syncthreads();

    auto proj_tile = [&](int th) {
      const _Float16* hsrc = (th & 1) ? hb1 : hb0;
      const _Float16* hrow = hsrc + (size_t)(16 * w + lr) * HID;
      f32x4 acc = {0.f, 0.f, 0.f, 0.f};
      #pragma unroll 8
      for (int kb = 0; kb < HID / 32; ++kb) {
        int k0 = kb * 32 + lg * 8;
        half8 a = *(const half8*)(hrow + k0);
        half8 bv = *(const half8*)(wp + lr * WP_LD + k0);
        acc = __builtin_amdgcn_mfma_f32_16x16x32_f16(a, bv, acc, 0, 0, 0);
      }
      float bz = pb[lr];
      #pragma unroll
      for (int r = 0; r < 4; ++r) {
        int n = 16 * w + lg * 4 + r;
        out[((size_t)n * T_LEN + th) * ODIM + p * 16 + lr] = acc[r] + bz;
      }
    };

    for (int t = 0; t < T_LEN; ++t) {
      if (t >= 1) proj_tile(t - 1);     // pipelined: project h_{t-1} during step t
      gbar(bar, bid, (unsigned)(t + 1));
    }
    proj_tile(T_LEN - 1);
  }
}

extern "C" void kernel_launch(void* const* d_in, const int* in_sizes, int n_in,
                              void* d_out, int out_size, void* d_ws, size_t ws_size,
                              hipStream_t stream) {
  const float* obs    = (const float*)d_in[0];
  const float* h0     = (const float*)d_in[1];
  const float* c0     = (const float*)d_in[2];
  const float* es     = (const float*)d_in[3];
  const float* W_ih   = (const float*)d_in[4];
  const float* W_hh   = (const float*)d_in[5];
  const float* b_ih   = (const float*)d_in[6];
  const float* b_hh   = (const float*)d_in[7];
  const float* W_proj = (const float*)d_in[8];
  const float* b_proj = (const float*)d_in[9];
  float* out = (float*)d_out;
  unsigned char* ws = (unsigned char*)d_ws;

  hipLaunchKernelGGL(init_kernel, dim3(64), dim3(256), 0, stream, h0, ws);
  hipLaunchKernelGGL(cvt_obs, dim3(4096), dim3(256), 0, stream, obs, ws);

  hipFuncSetAttribute((const void*)lstm_coop,
                      hipFuncAttributeMaxDynamicSharedMemorySize, LDS_BYTES);

  void* args[] = { (void*)&c0, (void*)&es, (void*)&W_ih, (void*)&W_hh,
                   (void*)&b_ih, (void*)&b_hh, (void*)&W_proj, (void*)&b_proj,
                   (void*)&out, (void*)&ws };
  hipLaunchCooperativeKernel((const void*)lstm_coop, dim3(TOT_WGS), dim3(256),
                             args, LDS_BYTES, stream);
}